// Round 1
// baseline (500.225 us; speedup 1.0000x reference)
//
#include <hip/hip_runtime.h>
#include <math.h>

#define PI_D 3.14159265358979323846

// ---------------------------------------------------------------------------
// Prep: transpose conv2_w [64][32][3][3] -> w2t[(c*9+k)*64 + oc]
//       transpose pred_w  [12544][10]    -> pwt[k*12544 + i]
// ---------------------------------------------------------------------------
__global__ __launch_bounds__(256) void prep_kernel(
    const float* __restrict__ w2, const float* __restrict__ pw,
    float* __restrict__ w2t, float* __restrict__ pwt)
{
    const int total = 18432 + 125440;
    for (int d = blockIdx.x * 256 + threadIdx.x; d < total; d += gridDim.x * 256) {
        if (d < 18432) {
            int oc = d & 63;
            int ck = d >> 6;
            int c  = ck / 9;
            int k  = ck - c * 9;
            w2t[d] = w2[(oc * 32 + c) * 9 + k];
        } else {
            int d2 = d - 18432;
            int k  = d2 / 12544;
            int i  = d2 - k * 12544;
            pwt[d2] = pw[i * 10 + k];
        }
    }
}

// ---------------------------------------------------------------------------
// Angle: per-image masked PCA via raw moments (f64 accum), store cos/sin of
// the inverse-rotation angle th = -angle_deg * pi/180.
// ---------------------------------------------------------------------------
__global__ __launch_bounds__(256) void angle_kernel(
    const float* __restrict__ x, float2* __restrict__ csn)
{
    const int b = blockIdx.x;
    const int t = threadIdx.x;
    const float* xb = x + b * 784;

    double S = 0, Sx = 0, Sy = 0, Sxx = 0, Sxy = 0, Syy = 0;
    for (int p = t; p < 784; p += 256) {
        float v = xb[p];
        if (v > 0.5f) {
            int j = p / 28;
            int i = p - j * 28;
            double gx = -14.0 + i * (28.0 / 27.0);
            double gy =  14.0 - j * (28.0 / 27.0);
            S   += 1.0;
            Sx  += gx;   Sy  += gy;
            Sxx += gx * gx; Sxy += gx * gy; Syy += gy * gy;
        }
    }
    // wave reduce (wave64)
    #pragma unroll
    for (int off = 32; off; off >>= 1) {
        S   += __shfl_down(S, off);
        Sx  += __shfl_down(Sx, off);
        Sy  += __shfl_down(Sy, off);
        Sxx += __shfl_down(Sxx, off);
        Sxy += __shfl_down(Sxy, off);
        Syy += __shfl_down(Syy, off);
    }
    __shared__ double red[4][6];
    const int lane = t & 63, w = t >> 6;
    if (lane == 0) {
        red[w][0] = S; red[w][1] = Sx; red[w][2] = Sy;
        red[w][3] = Sxx; red[w][4] = Sxy; red[w][5] = Syy;
    }
    __syncthreads();
    if (t == 0) {
        S   = red[0][0] + red[1][0] + red[2][0] + red[3][0];
        Sx  = red[0][1] + red[1][1] + red[2][1] + red[3][1];
        Sy  = red[0][2] + red[1][2] + red[2][2] + red[3][2];
        Sxx = red[0][3] + red[1][3] + red[2][3] + red[3][3];
        Sxy = red[0][4] + red[1][4] + red[2][4] + red[3][4];
        Syy = red[0][5] + red[1][5] + red[2][5] + red[3][5];

        double n  = (S < 1.0) ? 1.0 : S;
        double mx = Sx / n, my = Sy / n;
        double a  = Sxx - 2.0 * mx * Sx + mx * mx * S;
        double bb = Sxy - mx * Sy - my * Sx + mx * my * S;
        double cc = Syy - 2.0 * my * Sy + my * my * S;
        double lam = 0.5 * (a + cc) + sqrt(0.25 * (a - cc) * (a - cc) + bb * bb);
        double v1x = bb, v1y = lam - a;
        double v2x = lam - cc, v2y = bb;
        double n1 = v1x * v1x + v1y * v1y;
        double n2 = v2x * v2x + v2y * v2y;
        double vx, vy;
        if (n1 >= n2) { vx = v1x; vy = v1y; } else { vx = v2x; vy = v2y; }
        if (vx * vx + vy * vy < 1e-12) { vx = 1.0; vy = 0.0; }
        double ang_deg = atan2(vy, vx) * (180.0 / PI_D);
        double th = -ang_deg * (PI_D / 180.0);
        csn[b] = make_float2((float)cos(th), (float)sin(th));
    }
}

// ---------------------------------------------------------------------------
// Fused: rotate -> conv1(+ReLU) -> conv2(+ReLU, stride2, pad(0,1)) -> gemm
// One block (256 threads) per image. Lane = output channel (64) for conv2.
// ---------------------------------------------------------------------------
__global__ __launch_bounds__(256) void fused_kernel(
    const float* __restrict__ x,
    const float* __restrict__ w1, const float* __restrict__ b1,
    const float* __restrict__ b2,
    const float* __restrict__ w2t,   // [(c*9+k)*64 + oc]
    const float* __restrict__ pwt,   // [k*12544 + i]
    const float* __restrict__ pb,
    const float2* __restrict__ csn,
    float* __restrict__ out)
{
    const int b = blockIdx.x;
    const int t = threadIdx.x;
    const int lane = t & 63;     // = oc for conv2
    const int wv_id = t >> 6;    // wave 0..3

    __shared__ float smem[12608];
    float* img = smem;          // [28][32] raw image
    float* rot = smem + 896;    // [30][32] rotated, pad (1,1) both dims
    float* h1  = smem + 1856;   // [29][32] conv1 channel, pad (0,1) both dims

    const float* xb = x + b * 784;
    for (int p = t; p < 784; p += 256) {
        int y = p / 28, xx = p - y * 28;
        img[y * 32 + xx] = xb[p];
    }
    for (int p = t; p < 960; p += 256) rot[p] = 0.0f;
    for (int p = t; p < 928; p += 256) h1[p] = 0.0f;
    __syncthreads();

    // ---- rotate (bilinear, zero pad) into rot interior ----
    {
        const float2 cn = csn[b];
        const float cs = cn.x, sn = cn.y;
        for (int p = t; p < 784; p += 256) {
            int y = p / 28, xx = p - y * 28;
            float dxp = (float)xx - 13.5f;
            float dyp = (float)y  - 13.5f;
            float sx =  cs * dxp + sn * dyp + 13.5f;
            float sy = -sn * dxp + cs * dyp + 13.5f;
            float x0 = floorf(sx), y0 = floorf(sy);
            float wx1 = sx - x0, wx0 = 1.0f - wx1;
            float wy1 = sy - y0, wy0 = 1.0f - wy1;
            int ix0 = (int)x0, iy0 = (int)y0;
            int ix1 = ix0 + 1, iy1 = iy0 + 1;

            float v00 = 0.f, v01 = 0.f, v10 = 0.f, v11 = 0.f;
            {
                int cx0 = min(max(ix0, 0), 27), cy0 = min(max(iy0, 0), 27);
                int cx1 = min(max(ix1, 0), 27), cy1 = min(max(iy1, 0), 27);
                bool vx0 = (ix0 >= 0) & (ix0 <= 27);
                bool vx1 = (ix1 >= 0) & (ix1 <= 27);
                bool vy0 = (iy0 >= 0) & (iy0 <= 27);
                bool vy1 = (iy1 >= 0) & (iy1 <= 27);
                float a00 = img[cy0 * 32 + cx0];
                float a01 = img[cy0 * 32 + cx1];
                float a10 = img[cy1 * 32 + cx0];
                float a11 = img[cy1 * 32 + cx1];
                v00 = (vx0 & vy0) ? a00 : 0.f;
                v01 = (vx1 & vy0) ? a01 : 0.f;
                v10 = (vx0 & vy1) ? a10 : 0.f;
                v11 = (vx1 & vy1) ? a11 : 0.f;
            }
            float r = v00 * wy0 * wx0 + v01 * wy0 * wx1 +
                      v10 * wy1 * wx0 + v11 * wy1 * wx1;
            rot[(y + 1) * 32 + (xx + 1)] = r;
        }
    }
    __syncthreads();

    // ---- channel loop: conv1 (c) into h1, conv2 partial accumulate ----
    float acc[49];
    #pragma unroll
    for (int j = 0; j < 49; ++j) acc[j] = 0.0f;
    const float bias2 = b2[lane];
    const int sp_base = wv_id * 49;

    for (int c = 0; c < 32; ++c) {
        // conv1 weights (wave-uniform -> scalar loads)
        const float* w1c = w1 + c * 9;
        float k0 = w1c[0], k1 = w1c[1], k2 = w1c[2];
        float k3 = w1c[3], k4 = w1c[4], k5 = w1c[5];
        float k6 = w1c[6], k7 = w1c[7], k8 = w1c[8];
        float bb = b1[c];

        for (int p = t; p < 784; p += 256) {
            int y = p / 28, xx = p - y * 28;
            const float* rp = rot + y * 32 + xx;  // padded top-left
            float s = rp[0]  * k0 + rp[1]  * k1 + rp[2]  * k2 +
                      rp[32] * k3 + rp[33] * k4 + rp[34] * k5 +
                      rp[64] * k6 + rp[65] * k7 + rp[66] * k8;
            s += bb;
            h1[y * 32 + xx] = fmaxf(s, 0.0f);
        }
        __syncthreads();

        // conv2 partial: lane = oc, 9 coalesced weight loads
        float wv[9];
        #pragma unroll
        for (int k = 0; k < 9; ++k) wv[k] = w2t[(c * 9 + k) * 64 + lane];

        #pragma unroll
        for (int j = 0; j < 49; ++j) {
            int sp = sp_base + j;
            int oy = sp / 14;
            int ox = sp - oy * 14;
            // rows 2oy..2oy+2, cols 2ox..2ox+2 (pad high only)
            const float* hp = h1 + oy * 64 + ox * 2;
            float2 r0 = *(const float2*)(hp);
            float  e0 = hp[2];
            float2 r1 = *(const float2*)(hp + 32);
            float  e1 = hp[34];
            float2 r2 = *(const float2*)(hp + 64);
            float  e2 = hp[66];
            acc[j] += r0.x * wv[0] + r0.y * wv[1] + e0 * wv[2] +
                      r1.x * wv[3] + r1.y * wv[4] + e1 * wv[5] +
                      r2.x * wv[6] + r2.y * wv[7] + e2 * wv[8];
        }
        __syncthreads();
    }

    // ---- epilogue: bias + ReLU -> reps in LDS ----
    #pragma unroll
    for (int j = 0; j < 49; ++j) {
        int sp = sp_base + j;
        smem[lane * 196 + sp] = fmaxf(acc[j] + bias2, 0.0f);
    }
    __syncthreads();

    // ---- gemm: out[k] = sum_i reps[i] * pwt[k*12544 + i] ----
    float op[10];
    #pragma unroll
    for (int k = 0; k < 10; ++k) op[k] = 0.0f;
    #pragma unroll
    for (int j = 0; j < 49; ++j) {
        int i = t + 256 * j;
        float v = smem[i];
        #pragma unroll
        for (int k = 0; k < 10; ++k) op[k] += v * pwt[k * 12544 + i];
    }
    // wave reduce
    #pragma unroll
    for (int k = 0; k < 10; ++k) {
        float v = op[k];
        #pragma unroll
        for (int off = 32; off; off >>= 1) v += __shfl_down(v, off);
        op[k] = v;
    }
    if (lane == 0) {
        #pragma unroll
        for (int k = 0; k < 10; ++k) smem[12544 + wv_id * 10 + k] = op[k];
    }
    __syncthreads();
    if (t < 10) {
        float s = smem[12544 + t] + smem[12554 + t] + smem[12564 + t] + smem[12574 + t];
        out[b * 10 + t] = s + pb[t];
    }
}

// ---------------------------------------------------------------------------
extern "C" void kernel_launch(void* const* d_in, const int* in_sizes, int n_in,
                              void* d_out, int out_size, void* d_ws, size_t ws_size,
                              hipStream_t stream)
{
    const float* x   = (const float*)d_in[0];
    const float* w1  = (const float*)d_in[1];
    const float* b1  = (const float*)d_in[2];
    const float* w2  = (const float*)d_in[3];
    const float* b2  = (const float*)d_in[4];
    const float* pw  = (const float*)d_in[5];
    const float* pb  = (const float*)d_in[6];
    float* out = (float*)d_out;

    const int B = in_sizes[0] / 784;

    // workspace layout
    float2* csn = (float2*)d_ws;                       // B * 8 bytes
    float*  w2t = (float*)d_ws + 2 * B;                // 18432 floats
    float*  pwt = w2t + 18432;                         // 125440 floats

    prep_kernel<<<562, 256, 0, stream>>>(w2, pw, w2t, pwt);
    angle_kernel<<<B, 256, 0, stream>>>(x, csn);
    fused_kernel<<<B, 256, 0, stream>>>(x, w1, b1, b2, w2t, pwt, pb, csn, out);
}

// Round 3
// 245.311 us; speedup vs baseline: 2.0391x; 2.0391x over previous
//
#include <hip/hip_runtime.h>
#include <math.h>

#define PI_D 3.14159265358979323846

typedef __attribute__((ext_vector_type(8))) short short8;
typedef __attribute__((ext_vector_type(4))) float f32x4;

#define H1_OFF   3840
#define H1_ROWB  1920      // 29 cols * 64 B, padded to 128-multiple (bijective swizzle!)
#define H1_PLANE 55680     // 29 rows * 1920
#define LDS_BYTES (H1_OFF + 2*H1_PLANE)   // 115200

// byte offset of H1[plane][y][x][chunk of 8 ch], XOR-swizzled on bits [6:4]
// to spread the stride-128B conv2 A-reads across banks. Rows are 128-aligned
// and row stride is a 128-multiple, so each 128B window holds x=2w,2w+1 which
// share mask (w&7) -> XOR-by-constant within window -> bijection.
__device__ __forceinline__ int h1_byte(int plane, int y, int x, int chunk) {
    int b = H1_OFF + plane*H1_PLANE + y*H1_ROWB + x*64 + chunk*16;
    return b ^ (((x >> 1) & 7) << 4);
}

__device__ __forceinline__ unsigned short f32_bf16_rne(float f) {
    unsigned u = __float_as_uint(f);
    unsigned r = u + 0x7FFFu + ((u >> 16) & 1u);
    return (unsigned short)(r >> 16);
}

// ---------------------------------------------------------------------------
// Prep: pack conv2_w into MFMA B-fragments (hi/lo bf16 split) and pred_w into
// bf16 [k][sp*64+oc] layout.
// w2frag layout: frag f = (kk*4 + oct)*2 + split; ushort idx = f*512 + lane*8 + m
//   value = split(w2[oc=oct*16+(lane&15)][c=8*(lane>>4)+m][ky][kx]), kk=ky*3+kx
// pwt2 layout: ushort idx = k*12544 + (sp*64 + oc)  (bf16 of pw[(oc*196+sp)*10+k])
// ---------------------------------------------------------------------------
__global__ __launch_bounds__(256) void prep_kernel(
    const float* __restrict__ w2, const float* __restrict__ pw,
    unsigned short* __restrict__ w2frag, unsigned short* __restrict__ pwt2)
{
    const int NW2 = 9*4*2*64*8;   // 36864
    const int NPW = 10*12544;     // 125440
    for (int idx = blockIdx.x*256 + threadIdx.x; idx < NW2 + NPW; idx += gridDim.x*256) {
        if (idx < NW2) {
            int m = idx & 7;
            int l = (idx >> 3) & 63;
            int f = idx >> 9;        // 0..71
            int split = f & 1;
            int oct = (f >> 1) & 3;
            int kk = f >> 3;
            int oc = oct*16 + (l & 15);
            int c  = 8*(l >> 4) + m;
            float w = w2[(oc*32 + c)*9 + kk];
            unsigned short hu = f32_bf16_rne(w);
            unsigned short v;
            if (split == 0) {
                v = hu;
            } else {
                float hf = __uint_as_float(((unsigned)hu) << 16);
                v = f32_bf16_rne(w - hf);
            }
            w2frag[idx] = v;
        } else {
            int j = idx - NW2;
            int k = j / 12544;
            int i2 = j - k*12544;
            int sp = i2 >> 6;
            int oc = i2 & 63;
            pwt2[k*12544 + i2] = f32_bf16_rne(pw[(oc*196 + sp)*10 + k]);
        }
    }
}

// ---------------------------------------------------------------------------
// Angle: per-image masked PCA via raw moments (f64 accum), store cos/sin of
// the inverse-rotation angle th = -angle_deg * pi/180.  (unchanged, verified)
// ---------------------------------------------------------------------------
__global__ __launch_bounds__(256) void angle_kernel(
    const float* __restrict__ x, float2* __restrict__ csn)
{
    const int b = blockIdx.x;
    const int t = threadIdx.x;
    const float* xb = x + b * 784;

    double S = 0, Sx = 0, Sy = 0, Sxx = 0, Sxy = 0, Syy = 0;
    for (int p = t; p < 784; p += 256) {
        float v = xb[p];
        if (v > 0.5f) {
            int j = p / 28;
            int i = p - j * 28;
            double gx = -14.0 + i * (28.0 / 27.0);
            double gy =  14.0 - j * (28.0 / 27.0);
            S   += 1.0;
            Sx  += gx;   Sy  += gy;
            Sxx += gx * gx; Sxy += gx * gy; Syy += gy * gy;
        }
    }
    #pragma unroll
    for (int off = 32; off; off >>= 1) {
        S   += __shfl_down(S, off);
        Sx  += __shfl_down(Sx, off);
        Sy  += __shfl_down(Sy, off);
        Sxx += __shfl_down(Sxx, off);
        Sxy += __shfl_down(Sxy, off);
        Syy += __shfl_down(Syy, off);
    }
    __shared__ double red[4][6];
    const int lane = t & 63, w = t >> 6;
    if (lane == 0) {
        red[w][0] = S; red[w][1] = Sx; red[w][2] = Sy;
        red[w][3] = Sxx; red[w][4] = Sxy; red[w][5] = Syy;
    }
    __syncthreads();
    if (t == 0) {
        S   = red[0][0] + red[1][0] + red[2][0] + red[3][0];
        Sx  = red[0][1] + red[1][1] + red[2][1] + red[3][1];
        Sy  = red[0][2] + red[1][2] + red[2][2] + red[3][2];
        Sxx = red[0][3] + red[1][3] + red[2][3] + red[3][3];
        Sxy = red[0][4] + red[1][4] + red[2][4] + red[3][4];
        Syy = red[0][5] + red[1][5] + red[2][5] + red[3][5];

        double n  = (S < 1.0) ? 1.0 : S;
        double mx = Sx / n, my = Sy / n;
        double a  = Sxx - 2.0 * mx * Sx + mx * mx * S;
        double bb = Sxy - mx * Sy - my * Sx + mx * my * S;
        double cc = Syy - 2.0 * my * Sy + my * my * S;
        double lam = 0.5 * (a + cc) + sqrt(0.25 * (a - cc) * (a - cc) + bb * bb);
        double v1x = bb, v1y = lam - a;
        double v2x = lam - cc, v2y = bb;
        double n1 = v1x * v1x + v1y * v1y;
        double n2 = v2x * v2x + v2y * v2y;
        double vx, vy;
        if (n1 >= n2) { vx = v1x; vy = v1y; } else { vx = v2x; vy = v2y; }
        if (vx * vx + vy * vy < 1e-12) { vx = 1.0; vy = 0.0; }
        double ang_deg = atan2(vy, vx) * (180.0 / PI_D);
        double th = -ang_deg * (PI_D / 180.0);
        csn[b] = make_float2((float)cos(th), (float)sin(th));
    }
}

// ---------------------------------------------------------------------------
// Fused: rotate -> conv1 (f32, all 32 ch -> H1 bf16 hi/lo planes in LDS)
//        -> conv2 via MFMA 16x16x32 bf16 with 3-term hi/lo split
//        -> reps f32 in LDS -> pred gemm (bf16 weights) -> out
// One block (256 thr, 4 waves) per image. 1 block/CU (112.5 KB LDS).
// ---------------------------------------------------------------------------
__global__ __launch_bounds__(256, 1) void fused_kernel(
    const float* __restrict__ x,
    const float* __restrict__ w1, const float* __restrict__ b1,
    const float* __restrict__ b2,
    const unsigned short* __restrict__ w2frag,
    const unsigned short* __restrict__ pwt2,
    const float* __restrict__ pb,
    const float2* __restrict__ csn,
    float* __restrict__ out)
{
    __shared__ __align__(16) char lds[LDS_BYTES];
    float* rotf = (float*)lds;                    // [30][32] f32, pad (1,1)
    float* imgf = (float*)(lds + H1_OFF);         // [28][32] f32 (aliases H1, pre-conv1)
    float* reps = (float*)(lds + H1_OFF);         // 12544 f32 (aliases H1, post-conv2)
    float* red  = (float*)lds;                    // reduce scratch (aliases rot)

    const int b = blockIdx.x;
    const int t = threadIdx.x;
    const int lane = t & 63;
    const int wv = t >> 6;
    const int l15 = lane & 15;
    const int g   = lane >> 4;

    // ---- load image + zero rot ----
    const float* xb = x + b*784;
    for (int p = t; p < 784; p += 256) {
        int y = p/28, xx = p - y*28;
        imgf[y*32 + xx] = xb[p];
    }
    for (int p = t; p < 960; p += 256) rotf[p] = 0.0f;
    __syncthreads();

    // ---- rotate (bilinear, zero pad) into rot interior ----
    {
        const float2 cn = csn[b];
        const float cs = cn.x, sn = cn.y;
        for (int p = t; p < 784; p += 256) {
            int y = p/28, xx = p - y*28;
            float dxp = (float)xx - 13.5f;
            float dyp = (float)y  - 13.5f;
            float sx =  cs * dxp + sn * dyp + 13.5f;
            float sy = -sn * dxp + cs * dyp + 13.5f;
            float x0 = floorf(sx), y0 = floorf(sy);
            float wx1 = sx - x0, wx0 = 1.0f - wx1;
            float wy1 = sy - y0, wy0 = 1.0f - wy1;
            int ix0 = (int)x0, iy0 = (int)y0;
            int ix1 = ix0 + 1, iy1 = iy0 + 1;
            int cx0 = min(max(ix0, 0), 27), cy0 = min(max(iy0, 0), 27);
            int cx1 = min(max(ix1, 0), 27), cy1 = min(max(iy1, 0), 27);
            bool vx0 = (ix0 >= 0) & (ix0 <= 27);
            bool vx1 = (ix1 >= 0) & (ix1 <= 27);
            bool vy0 = (iy0 >= 0) & (iy0 <= 27);
            bool vy1 = (iy1 >= 0) & (iy1 <= 27);
            float a00 = imgf[cy0*32 + cx0];
            float a01 = imgf[cy0*32 + cx1];
            float a10 = imgf[cy1*32 + cx0];
            float a11 = imgf[cy1*32 + cx1];
            float v00 = (vx0 & vy0) ? a00 : 0.f;
            float v01 = (vx1 & vy0) ? a01 : 0.f;
            float v10 = (vx0 & vy1) ? a10 : 0.f;
            float v11 = (vx1 & vy1) ? a11 : 0.f;
            float r = v00*wy0*wx0 + v01*wy0*wx1 + v10*wy1*wx0 + v11*wy1*wx1;
            rotf[(y + 1)*32 + (xx + 1)] = r;
        }
    }
    __syncthreads();   // img no longer needed; H1 region free

    // ---- zero H1 pads (row 28 and col 28, both planes) ----
    // disjoint from conv1's (y<28, x<28) writes now that swizzle is bijective
    {
        short8 z8 = {0,0,0,0,0,0,0,0};
        for (int z = t; z < 456; z += 256) {
            int plane = z / 228;
            int r = z - plane*228;
            int cell = r >> 2;
            int chunk = r & 3;
            int y, xx;
            if (cell < 29) { y = 28; xx = cell; } else { y = cell - 29; xx = 28; }
            *(short8*)(lds + h1_byte(plane, y, xx, chunk)) = z8;
        }
    }

    // ---- conv1: all 32 channels per position -> H1 hi/lo bf16 planes ----
    // per-wave balanced: wave wv handles positions [wv*196, wv*196+196)
    for (int pi = lane; pi < 196; pi += 64) {
        int p = wv*196 + pi;
        int py = p/28, px = p - py*28;
        const float* rp = rotf + py*32 + px;   // padded top-left
        float r0 = rp[0],  r1 = rp[1],  r2 = rp[2];
        float r3 = rp[32], r4 = rp[33], r5 = rp[34];
        float r6 = rp[64], r7 = rp[65], r8 = rp[66];
        #pragma unroll
        for (int c8 = 0; c8 < 4; ++c8) {
            short8 vh, vl;
            #pragma unroll
            for (int cc = 0; cc < 8; ++cc) {
                int c = c8*8 + cc;
                const float* wc = w1 + c*9;
                float s = b1[c];
                s = fmaf(wc[0], r0, s); s = fmaf(wc[1], r1, s); s = fmaf(wc[2], r2, s);
                s = fmaf(wc[3], r3, s); s = fmaf(wc[4], r4, s); s = fmaf(wc[5], r5, s);
                s = fmaf(wc[6], r6, s); s = fmaf(wc[7], r7, s); s = fmaf(wc[8], r8, s);
                s = fmaxf(s, 0.0f);
                unsigned short hu = f32_bf16_rne(s);
                float hf = __uint_as_float(((unsigned)hu) << 16);
                unsigned short lu = f32_bf16_rne(s - hf);
                vh[cc] = (short)hu;
                vl[cc] = (short)lu;
            }
            *(short8*)(lds + h1_byte(0, py, px, c8)) = vh;
            *(short8*)(lds + h1_byte(1, py, px, c8)) = vl;
        }
    }
    __syncthreads();

    // ---- conv2 via MFMA: 13 sp-tiles x 4 oc-tiles = 52 units, 13/wave ----
    f32x4 acc[13];
    #pragma unroll
    for (int q = 0; q < 13; ++q) acc[q] = (f32x4){0.f, 0.f, 0.f, 0.f};
    const int u0 = wv*13;

    for (int kk = 0; kk < 9; ++kk) {
        int ky = kk/3;
        int kx = kk - ky*3;
        short8 ah, al;
        #pragma unroll
        for (int q = 0; q < 13; ++q) {
            int u = u0 + q;
            int tile = u >> 2, oct = u & 3;
            if (q == 0 || (u & 3) == 0) {   // tile changed -> reload A fragment
                int sp = tile*16 + l15;
                sp = sp > 195 ? 195 : sp;   // clamp garbage rows (discarded later)
                int oy = sp/14, ox = sp - oy*14;
                int y = 2*oy + ky, xx = 2*ox + kx;
                ah = *(const short8*)(lds + h1_byte(0, y, xx, g));
                al = *(const short8*)(lds + h1_byte(1, y, xx, g));
            }
            const short8* bp = (const short8*)(w2frag + (kk*4 + oct)*1024 + lane*8);
            short8 bh = bp[0];
            short8 bl = bp[64];   // +512 ushorts = lo-split fragment
            acc[q] = __builtin_amdgcn_mfma_f32_16x16x32_bf16(ah, bh, acc[q], 0, 0, 0);
            acc[q] = __builtin_amdgcn_mfma_f32_16x16x32_bf16(ah, bl, acc[q], 0, 0, 0);
            acc[q] = __builtin_amdgcn_mfma_f32_16x16x32_bf16(al, bh, acc[q], 0, 0, 0);
        }
    }
    __syncthreads();   // all H1 reads done; reps may overwrite

    // ---- epilogue: bias + ReLU -> reps[sp*64 + oc] f32 ----
    #pragma unroll
    for (int q = 0; q < 13; ++q) {
        int u = u0 + q;
        int tile = u >> 2, oct = u & 3;
        int oc = oct*16 + l15;
        float bias = b2[oc];
        int sp0 = tile*16 + 4*g;
        #pragma unroll
        for (int j = 0; j < 4; ++j) {
            int sp = sp0 + j;
            if (sp < 196) reps[sp*64 + oc] = fmaxf(acc[q][j] + bias, 0.0f);
        }
    }
    __syncthreads();

    // ---- pred gemm: out[k] = sum_i reps[i] * pw[i][k], bf16 weights ----
    float a10[10];
    #pragma unroll
    for (int k = 0; k < 10; ++k) a10[k] = 0.0f;
    const unsigned* pw32 = (const unsigned*)pwt2;   // [k][6272] bf16-pairs
    for (int j = 0; j < 25; ++j) {
        int ip = t + 256*j;     // pair index: elements 2*ip, 2*ip+1
        if (ip < 6272) {
            float2 r = *(const float2*)(reps + 2*ip);
            #pragma unroll
            for (int k = 0; k < 10; ++k) {
                unsigned u = pw32[k*6272 + ip];
                float plo = __uint_as_float(u << 16);
                float phi = __uint_as_float(u & 0xFFFF0000u);
                a10[k] = fmaf(r.x, plo, fmaf(r.y, phi, a10[k]));
            }
        }
    }
    #pragma unroll
    for (int k = 0; k < 10; ++k) {
        float v = a10[k];
        #pragma unroll
        for (int off = 32; off; off >>= 1) v += __shfl_down(v, off);
        a10[k] = v;
    }
    if (lane == 0) {
        #pragma unroll
        for (int k = 0; k < 10; ++k) red[wv*10 + k] = a10[k];
    }
    __syncthreads();
    if (t < 10) {
        out[b*10 + t] = red[t] + red[10 + t] + red[20 + t] + red[30 + t] + pb[t];
    }
}

// ---------------------------------------------------------------------------
extern "C" void kernel_launch(void* const* d_in, const int* in_sizes, int n_in,
                              void* d_out, int out_size, void* d_ws, size_t ws_size,
                              hipStream_t stream)
{
    const float* x   = (const float*)d_in[0];
    const float* w1  = (const float*)d_in[1];
    const float* b1  = (const float*)d_in[2];
    const float* w2  = (const float*)d_in[3];
    const float* b2  = (const float*)d_in[4];
    const float* pw  = (const float*)d_in[5];
    const float* pb  = (const float*)d_in[6];
    float* out = (float*)d_out;

    const int B = in_sizes[0] / 784;

    // workspace layout (bytes): csn [B*8] | w2frag [73728] | pwt2 [250880]
    char* wsb = (char*)d_ws;
    float2* csn = (float2*)wsb;
    unsigned short* w2frag = (unsigned short*)(wsb + (size_t)B*8);
    unsigned short* pwt2   = (unsigned short*)(wsb + (size_t)B*8 + 73728);

    prep_kernel<<<634, 256, 0, stream>>>(w2, pw, w2frag, pwt2);
    angle_kernel<<<B, 256, 0, stream>>>(x, csn);
    fused_kernel<<<B, 256, 0, stream>>>(x, w1, b1, b2, w2frag, pwt2, pb, csn, out);
}

// Round 4
// 163.083 us; speedup vs baseline: 3.0673x; 1.5042x over previous
//
#include <hip/hip_runtime.h>
#include <math.h>

#define PI_D 3.14159265358979323846

typedef __attribute__((ext_vector_type(8))) short short8;
typedef __attribute__((ext_vector_type(4))) float f32x4;

#define H1_OFF   3840
#define H1_ROWB  1920      // 29 cols * 64 B, padded to 128-multiple (bijective swizzle)
#define H1_PLANE 55680     // 29 rows * 1920
#define LDS_BYTES (H1_OFF + 2*H1_PLANE)   // 115200

// byte offset of H1[plane][y][x][chunk of 8 ch], XOR-swizzled on bits [6:4].
__device__ __forceinline__ int h1_byte(int plane, int y, int x, int chunk) {
    int b = H1_OFF + plane*H1_PLANE + y*H1_ROWB + x*64 + chunk*16;
    return b ^ (((x >> 1) & 7) << 4);
}

__device__ __forceinline__ unsigned short f32_bf16_rne(float f) {
    unsigned u = __float_as_uint(f);
    unsigned r = u + 0x7FFFu + ((u >> 16) & 1u);
    return (unsigned short)(r >> 16);
}

// ---------------------------------------------------------------------------
// Prep: pack conv2_w into MFMA B-fragments (hi/lo bf16 split) and pred_w into
// bf16 [k][sp*64+oc] layout.  (unchanged, verified)
// ---------------------------------------------------------------------------
__global__ __launch_bounds__(256) void prep_kernel(
    const float* __restrict__ w2, const float* __restrict__ pw,
    unsigned short* __restrict__ w2frag, unsigned short* __restrict__ pwt2)
{
    const int NW2 = 9*4*2*64*8;   // 36864
    const int NPW = 10*12544;     // 125440
    for (int idx = blockIdx.x*256 + threadIdx.x; idx < NW2 + NPW; idx += gridDim.x*256) {
        if (idx < NW2) {
            int m = idx & 7;
            int l = (idx >> 3) & 63;
            int f = idx >> 9;        // 0..71
            int split = f & 1;
            int oct = (f >> 1) & 3;
            int kk = f >> 3;
            int oc = oct*16 + (l & 15);
            int c  = 8*(l >> 4) + m;
            float w = w2[(oc*32 + c)*9 + kk];
            unsigned short hu = f32_bf16_rne(w);
            unsigned short v;
            if (split == 0) {
                v = hu;
            } else {
                float hf = __uint_as_float(((unsigned)hu) << 16);
                v = f32_bf16_rne(w - hf);
            }
            w2frag[idx] = v;
        } else {
            int j = idx - NW2;
            int k = j / 12544;
            int i2 = j - k*12544;
            int sp = i2 >> 6;
            int oc = i2 & 63;
            pwt2[k*12544 + i2] = f32_bf16_rne(pw[(oc*196 + sp)*10 + k]);
        }
    }
}

// ---------------------------------------------------------------------------
// Angle: per-image masked PCA via raw moments (f64 accum). (unchanged)
// ---------------------------------------------------------------------------
__global__ __launch_bounds__(256) void angle_kernel(
    const float* __restrict__ x, float2* __restrict__ csn)
{
    const int b = blockIdx.x;
    const int t = threadIdx.x;
    const float* xb = x + b * 784;

    double S = 0, Sx = 0, Sy = 0, Sxx = 0, Sxy = 0, Syy = 0;
    for (int p = t; p < 784; p += 256) {
        float v = xb[p];
        if (v > 0.5f) {
            int j = p / 28;
            int i = p - j * 28;
            double gx = -14.0 + i * (28.0 / 27.0);
            double gy =  14.0 - j * (28.0 / 27.0);
            S   += 1.0;
            Sx  += gx;   Sy  += gy;
            Sxx += gx * gx; Sxy += gx * gy; Syy += gy * gy;
        }
    }
    #pragma unroll
    for (int off = 32; off; off >>= 1) {
        S   += __shfl_down(S, off);
        Sx  += __shfl_down(Sx, off);
        Sy  += __shfl_down(Sy, off);
        Sxx += __shfl_down(Sxx, off);
        Sxy += __shfl_down(Sxy, off);
        Syy += __shfl_down(Syy, off);
    }
    __shared__ double red[4][6];
    const int lane = t & 63, w = t >> 6;
    if (lane == 0) {
        red[w][0] = S; red[w][1] = Sx; red[w][2] = Sy;
        red[w][3] = Sxx; red[w][4] = Sxy; red[w][5] = Syy;
    }
    __syncthreads();
    if (t == 0) {
        S   = red[0][0] + red[1][0] + red[2][0] + red[3][0];
        Sx  = red[0][1] + red[1][1] + red[2][1] + red[3][1];
        Sy  = red[0][2] + red[1][2] + red[2][2] + red[3][2];
        Sxx = red[0][3] + red[1][3] + red[2][3] + red[3][3];
        Sxy = red[0][4] + red[1][4] + red[2][4] + red[3][4];
        Syy = red[0][5] + red[1][5] + red[2][5] + red[3][5];

        double n  = (S < 1.0) ? 1.0 : S;
        double mx = Sx / n, my = Sy / n;
        double a  = Sxx - 2.0 * mx * Sx + mx * mx * S;
        double bb = Sxy - mx * Sy - my * Sx + mx * my * S;
        double cc = Syy - 2.0 * my * Sy + my * my * S;
        double lam = 0.5 * (a + cc) + sqrt(0.25 * (a - cc) * (a - cc) + bb * bb);
        double v1x = bb, v1y = lam - a;
        double v2x = lam - cc, v2y = bb;
        double n1 = v1x * v1x + v1y * v1y;
        double n2 = v2x * v2x + v2y * v2y;
        double vx, vy;
        if (n1 >= n2) { vx = v1x; vy = v1y; } else { vx = v2x; vy = v2y; }
        if (vx * vx + vy * vy < 1e-12) { vx = 1.0; vy = 0.0; }
        double ang_deg = atan2(vy, vx) * (180.0 / PI_D);
        double th = -ang_deg * (PI_D / 180.0);
        csn[b] = make_float2((float)cos(th), (float)sin(th));
    }
}

// ---------------------------------------------------------------------------
// Fused kernel, 1024 threads (16 waves, 4 waves/SIMD) per image.
// rotate -> conv1 (f32 -> H1 bf16 hi/lo planes) -> conv2 MFMA 3-term split
// -> reps f32 -> pred gemm.  1 block/CU (112.5 KB LDS).
// ---------------------------------------------------------------------------
__global__ __launch_bounds__(1024) void fused_kernel(
    const float* __restrict__ x,
    const float* __restrict__ w1, const float* __restrict__ b1,
    const float* __restrict__ b2,
    const unsigned short* __restrict__ w2frag,
    const unsigned short* __restrict__ pwt2,
    const float* __restrict__ pb,
    const float2* __restrict__ csn,
    float* __restrict__ out)
{
    __shared__ __align__(16) char lds[LDS_BYTES];
    float* rotf = (float*)lds;                    // [30][32] f32, pad (1,1)
    float* imgf = (float*)(lds + H1_OFF);         // [28][32] f32 (aliases H1)
    float* reps = (float*)(lds + H1_OFF);         // 12544 f32 (aliases H1)
    float* red  = (float*)lds;                    // reduce scratch (aliases rot)

    const int b = blockIdx.x;
    const int t = threadIdx.x;
    const int lane = t & 63;
    const int wv = t >> 6;       // 0..15
    const int l15 = lane & 15;
    const int g   = lane >> 4;

    // ---- load image + zero rot (one element per thread) ----
    const float* xb = x + b*784;
    if (t < 784) {
        int y = t/28, xx = t - y*28;
        imgf[y*32 + xx] = xb[t];
    }
    if (t < 960) rotf[t] = 0.0f;
    __syncthreads();

    // ---- rotate (bilinear, zero pad): one position per thread ----
    if (t < 784) {
        const float2 cn = csn[b];
        const float cs = cn.x, sn = cn.y;
        int y = t/28, xx = t - y*28;
        float dxp = (float)xx - 13.5f;
        float dyp = (float)y  - 13.5f;
        float sx =  cs * dxp + sn * dyp + 13.5f;
        float sy = -sn * dxp + cs * dyp + 13.5f;
        float x0 = floorf(sx), y0 = floorf(sy);
        float wx1 = sx - x0, wx0 = 1.0f - wx1;
        float wy1 = sy - y0, wy0 = 1.0f - wy1;
        int ix0 = (int)x0, iy0 = (int)y0;
        int ix1 = ix0 + 1, iy1 = iy0 + 1;
        int cx0 = min(max(ix0, 0), 27), cy0 = min(max(iy0, 0), 27);
        int cx1 = min(max(ix1, 0), 27), cy1 = min(max(iy1, 0), 27);
        bool vx0 = (ix0 >= 0) & (ix0 <= 27);
        bool vx1 = (ix1 >= 0) & (ix1 <= 27);
        bool vy0 = (iy0 >= 0) & (iy0 <= 27);
        bool vy1 = (iy1 >= 0) & (iy1 <= 27);
        float a00 = imgf[cy0*32 + cx0];
        float a01 = imgf[cy0*32 + cx1];
        float a10 = imgf[cy1*32 + cx0];
        float a11 = imgf[cy1*32 + cx1];
        float v00 = (vx0 & vy0) ? a00 : 0.f;
        float v01 = (vx1 & vy0) ? a01 : 0.f;
        float v10 = (vx0 & vy1) ? a10 : 0.f;
        float v11 = (vx1 & vy1) ? a11 : 0.f;
        float r = v00*wy0*wx0 + v01*wy0*wx1 + v10*wy1*wx0 + v11*wy1*wx1;
        rotf[(y + 1)*32 + (xx + 1)] = r;
    }
    __syncthreads();   // imgf reads done; H1 region free

    // ---- zero H1 pads (row 28 and col 28, both planes) ----
    if (t < 456) {
        short8 z8 = {0,0,0,0,0,0,0,0};
        int plane = t / 228;
        int r = t - plane*228;
        int cell = r >> 2;
        int chunk = r & 3;
        int y, xx;
        if (cell < 29) { y = 28; xx = cell; } else { y = cell - 29; xx = 28; }
        *(short8*)(lds + h1_byte(plane, y, xx, chunk)) = z8;
    }

    // ---- conv1: one position per lane (49 per wave), wave-uniform weights ----
    if (lane < 49) {
        int p = wv*49 + lane;
        int py = p/28, px = p - py*28;
        const float* rp = rotf + py*32 + px;   // padded top-left
        float r0 = rp[0],  r1 = rp[1],  r2 = rp[2];
        float r3 = rp[32], r4 = rp[33], r5 = rp[34];
        float r6 = rp[64], r7 = rp[65], r8 = rp[66];
        #pragma unroll
        for (int c8 = 0; c8 < 4; ++c8) {
            short8 vh, vl;
            #pragma unroll
            for (int cc = 0; cc < 8; ++cc) {
                int c = c8*8 + cc;
                const float* wc = w1 + c*9;
                float s = b1[c];
                s = fmaf(wc[0], r0, s); s = fmaf(wc[1], r1, s); s = fmaf(wc[2], r2, s);
                s = fmaf(wc[3], r3, s); s = fmaf(wc[4], r4, s); s = fmaf(wc[5], r5, s);
                s = fmaf(wc[6], r6, s); s = fmaf(wc[7], r7, s); s = fmaf(wc[8], r8, s);
                s = fmaxf(s, 0.0f);
                unsigned short hu = f32_bf16_rne(s);
                float hf = __uint_as_float(((unsigned)hu) << 16);
                unsigned short lu = f32_bf16_rne(s - hf);
                vh[cc] = (short)hu;
                vl[cc] = (short)lu;
            }
            *(short8*)(lds + h1_byte(0, py, px, c8)) = vh;
            *(short8*)(lds + h1_byte(1, py, px, c8)) = vl;
        }
    }
    __syncthreads();

    // ---- conv2 via MFMA: 52 units (13 sp-tiles x 4 oc-octs) over 16 waves ----
    // ordering u = tile*4 + oct -> waves are (mostly) tile-stationary.
    f32x4 acc[4];
    #pragma unroll
    for (int q = 0; q < 4; ++q) acc[q] = (f32x4){0.f, 0.f, 0.f, 0.f};
    const int u0 = (wv < 4) ? (4*wv) : (16 + 3*(wv - 4));
    const int nq = (wv < 4) ? 4 : 3;

    for (int kk = 0; kk < 9; ++kk) {
        int ky = kk/3;
        int kx = kk - ky*3;
        short8 ah, al;
        int lastTile = -1;
        #pragma unroll
        for (int q = 0; q < 4; ++q) {
            if (q < nq) {
                int u = u0 + q;
                int tile = u >> 2, oct = u & 3;
                if (tile != lastTile) {
                    int sp = tile*16 + l15;
                    sp = sp > 195 ? 195 : sp;   // clamp garbage rows (discarded later)
                    int oy = sp/14, ox = sp - oy*14;
                    int y = 2*oy + ky, xx = 2*ox + kx;
                    ah = *(const short8*)(lds + h1_byte(0, y, xx, g));
                    al = *(const short8*)(lds + h1_byte(1, y, xx, g));
                    lastTile = tile;
                }
                const short8* bp = (const short8*)(w2frag + (kk*4 + oct)*1024 + lane*8);
                short8 bh = bp[0];
                short8 bl = bp[64];   // +512 ushorts = lo-split fragment
                acc[q] = __builtin_amdgcn_mfma_f32_16x16x32_bf16(ah, bh, acc[q], 0, 0, 0);
                acc[q] = __builtin_amdgcn_mfma_f32_16x16x32_bf16(ah, bl, acc[q], 0, 0, 0);
                acc[q] = __builtin_amdgcn_mfma_f32_16x16x32_bf16(al, bh, acc[q], 0, 0, 0);
            }
        }
    }
    __syncthreads();   // all H1 reads done; reps may overwrite

    // ---- epilogue: bias + ReLU -> reps[sp*64 + oc] f32 ----
    #pragma unroll
    for (int q = 0; q < 4; ++q) {
        if (q < nq) {
            int u = u0 + q;
            int tile = u >> 2, oct = u & 3;
            int oc = oct*16 + l15;
            float bias = b2[oc];
            int sp0 = tile*16 + 4*g;
            #pragma unroll
            for (int j = 0; j < 4; ++j) {
                int sp = sp0 + j;
                if (sp < 196) reps[sp*64 + oc] = fmaxf(acc[q][j] + bias, 0.0f);
            }
        }
    }
    __syncthreads();

    // ---- pred gemm: out[k] = sum_i reps[i] * pw[i][k], bf16 weights ----
    float a10[10];
    #pragma unroll
    for (int k = 0; k < 10; ++k) a10[k] = 0.0f;
    const unsigned* pw32 = (const unsigned*)pwt2;   // [k][6272] bf16-pairs
    for (int ip = t; ip < 6272; ip += 1024) {
        float2 r = *(const float2*)(reps + 2*ip);
        #pragma unroll
        for (int k = 0; k < 10; ++k) {
            unsigned u = pw32[k*6272 + ip];
            float plo = __uint_as_float(u << 16);
            float phi = __uint_as_float(u & 0xFFFF0000u);
            a10[k] = fmaf(r.x, plo, fmaf(r.y, phi, a10[k]));
        }
    }
    #pragma unroll
    for (int k = 0; k < 10; ++k) {
        float v = a10[k];
        #pragma unroll
        for (int off = 32; off; off >>= 1) v += __shfl_down(v, off);
        a10[k] = v;
    }
    if (lane == 0) {
        #pragma unroll
        for (int k = 0; k < 10; ++k) red[wv*10 + k] = a10[k];
    }
    __syncthreads();
    if (t < 10) {
        float s = pb[t];
        #pragma unroll
        for (int w = 0; w < 16; ++w) s += red[w*10 + t];
        out[b*10 + t] = s;
    }
}

// ---------------------------------------------------------------------------
extern "C" void kernel_launch(void* const* d_in, const int* in_sizes, int n_in,
                              void* d_out, int out_size, void* d_ws, size_t ws_size,
                              hipStream_t stream)
{
    const float* x   = (const float*)d_in[0];
    const float* w1  = (const float*)d_in[1];
    const float* b1  = (const float*)d_in[2];
    const float* w2  = (const float*)d_in[3];
    const float* b2  = (const float*)d_in[4];
    const float* pw  = (const float*)d_in[5];
    const float* pb  = (const float*)d_in[6];
    float* out = (float*)d_out;

    const int B = in_sizes[0] / 784;

    // workspace layout (bytes): csn [B*8] | w2frag [73728] | pwt2 [250880]
    char* wsb = (char*)d_ws;
    float2* csn = (float2*)wsb;
    unsigned short* w2frag = (unsigned short*)(wsb + (size_t)B*8);
    unsigned short* pwt2   = (unsigned short*)(wsb + (size_t)B*8 + 73728);

    prep_kernel<<<634, 256, 0, stream>>>(w2, pw, w2frag, pwt2);
    angle_kernel<<<B, 256, 0, stream>>>(x, csn);
    fused_kernel<<<B, 1024, 0, stream>>>(x, w1, b1, b2, w2frag, pwt2, pb, csn, out);
}

// Round 5
// 95.018 us; speedup vs baseline: 5.2645x; 1.7163x over previous
//
#include <hip/hip_runtime.h>
#include <math.h>

#define PI_D 3.14159265358979323846

typedef __attribute__((ext_vector_type(8))) short short8;
typedef __attribute__((ext_vector_type(4))) float f32x4;
typedef __attribute__((ext_vector_type(8))) _Float16 half8;
typedef __attribute__((ext_vector_type(4))) _Float16 half4;
typedef __attribute__((ext_vector_type(2))) _Float16 half2v;

#define H1_OFF   3840
#define H1_ROWB  1920      // 29 cols * 64 B (32ch * 2B f16), 128-multiple -> bijective swizzle
#define LDS_BYTES (H1_OFF + 29*H1_ROWB)   // 3840 + 55680 = 59520
#define REPS_OFF 0         // 12544 f16 = 25088 B (aliases rot + H1 front, both dead by then)
#define RED_OFF  25344     // 16 waves * 10 f32 = 640 B

// byte offset of H1[y][x][chunk of 8 ch], XOR-swizzled on bits [6:4].
__device__ __forceinline__ int h1_byte(int y, int x, int chunk) {
    int b = H1_OFF + y*H1_ROWB + x*64 + chunk*16;
    return b ^ (((x >> 1) & 7) << 4);
}

// ---------------------------------------------------------------------------
// Prep: pack conv2_w into f16 MFMA B-fragments and pred_w into f16 [k][i2]
// w2frag: frag f = kk*4 + oct; ushort idx = f*512 + lane*8 + m
//   value = f16(w2[oc=oct*16+(lane&15)][c=8*(lane>>4)+m][kk])
// pwt2:   ushort idx = k*12544 + i2  where i2 = oc*196 + sp  (matches reps16)
// ---------------------------------------------------------------------------
__global__ __launch_bounds__(256) void prep_kernel(
    const float* __restrict__ w2, const float* __restrict__ pw,
    unsigned short* __restrict__ w2frag, unsigned short* __restrict__ pwt2)
{
    const int NW2 = 9*4*64*8;     // 18432
    const int NPW = 10*12544;     // 125440
    for (int idx = blockIdx.x*256 + threadIdx.x; idx < NW2 + NPW; idx += gridDim.x*256) {
        if (idx < NW2) {
            int m = idx & 7;
            int l = (idx >> 3) & 63;
            int f = idx >> 9;        // 0..35
            int oct = f & 3;
            int kk = f >> 2;
            int oc = oct*16 + (l & 15);
            int c  = 8*(l >> 4) + m;
            _Float16 h = (_Float16)w2[(oc*32 + c)*9 + kk];
            w2frag[idx] = __builtin_bit_cast(unsigned short, h);
        } else {
            int j = idx - NW2;
            int k = j / 12544;
            int i2 = j - k*12544;    // i2 = oc*196 + sp
            _Float16 h = (_Float16)pw[i2*10 + k];
            pwt2[k*12544 + i2] = __builtin_bit_cast(unsigned short, h);
        }
    }
}

// ---------------------------------------------------------------------------
// Angle: per-image masked PCA via raw moments (f64 accum). (unchanged, verified)
// ---------------------------------------------------------------------------
__global__ __launch_bounds__(256) void angle_kernel(
    const float* __restrict__ x, float2* __restrict__ csn)
{
    const int b = blockIdx.x;
    const int t = threadIdx.x;
    const float* xb = x + b * 784;

    double S = 0, Sx = 0, Sy = 0, Sxx = 0, Sxy = 0, Syy = 0;
    for (int p = t; p < 784; p += 256) {
        float v = xb[p];
        if (v > 0.5f) {
            int j = p / 28;
            int i = p - j * 28;
            double gx = -14.0 + i * (28.0 / 27.0);
            double gy =  14.0 - j * (28.0 / 27.0);
            S   += 1.0;
            Sx  += gx;   Sy  += gy;
            Sxx += gx * gx; Sxy += gx * gy; Syy += gy * gy;
        }
    }
    #pragma unroll
    for (int off = 32; off; off >>= 1) {
        S   += __shfl_down(S, off);
        Sx  += __shfl_down(Sx, off);
        Sy  += __shfl_down(Sy, off);
        Sxx += __shfl_down(Sxx, off);
        Sxy += __shfl_down(Sxy, off);
        Syy += __shfl_down(Syy, off);
    }
    __shared__ double red[4][6];
    const int lane = t & 63, w = t >> 6;
    if (lane == 0) {
        red[w][0] = S; red[w][1] = Sx; red[w][2] = Sy;
        red[w][3] = Sxx; red[w][4] = Sxy; red[w][5] = Syy;
    }
    __syncthreads();
    if (t == 0) {
        S   = red[0][0] + red[1][0] + red[2][0] + red[3][0];
        Sx  = red[0][1] + red[1][1] + red[2][1] + red[3][1];
        Sy  = red[0][2] + red[1][2] + red[2][2] + red[3][2];
        Sxx = red[0][3] + red[1][3] + red[2][3] + red[3][3];
        Sxy = red[0][4] + red[1][4] + red[2][4] + red[3][4];
        Syy = red[0][5] + red[1][5] + red[2][5] + red[3][5];

        double n  = (S < 1.0) ? 1.0 : S;
        double mx = Sx / n, my = Sy / n;
        double a  = Sxx - 2.0 * mx * Sx + mx * mx * S;
        double bb = Sxy - mx * Sy - my * Sx + mx * my * S;
        double cc = Syy - 2.0 * my * Sy + my * my * S;
        double lam = 0.5 * (a + cc) + sqrt(0.25 * (a - cc) * (a - cc) + bb * bb);
        double v1x = bb, v1y = lam - a;
        double v2x = lam - cc, v2y = bb;
        double n1 = v1x * v1x + v1y * v1y;
        double n2 = v2x * v2x + v2y * v2y;
        double vx, vy;
        if (n1 >= n2) { vx = v1x; vy = v1y; } else { vx = v2x; vy = v2y; }
        if (vx * vx + vy * vy < 1e-12) { vx = 1.0; vy = 0.0; }
        double ang_deg = atan2(vy, vx) * (180.0 / PI_D);
        double th = -ang_deg * (PI_D / 180.0);
        csn[b] = make_float2((float)cos(th), (float)sin(th));
    }
}

// ---------------------------------------------------------------------------
// Fused kernel, 1024 threads (16 waves), 2 blocks/CU (58.1 KB LDS, <=64 VGPR).
// rotate -> conv1 (f32 -> H1 f16 plane) -> conv2 MFMA f16 -> reps f16 -> pred gemm
// ---------------------------------------------------------------------------
__global__ __launch_bounds__(1024, 8) void fused_kernel(
    const float* __restrict__ x,
    const float* __restrict__ w1, const float* __restrict__ b1,
    const float* __restrict__ b2,
    const unsigned short* __restrict__ w2frag,
    const unsigned short* __restrict__ pwt2,
    const float* __restrict__ pb,
    const float2* __restrict__ csn,
    float* __restrict__ out)
{
    __shared__ __align__(16) char lds[LDS_BYTES];
    float* rotf = (float*)lds;                    // [30][32] f32, pad (1,1)
    float* imgf = (float*)(lds + H1_OFF);         // [28][32] f32 (aliases H1 front)
    _Float16* reps16 = (_Float16*)(lds + REPS_OFF); // 12544 f16 (aliases rot+H1 front)
    float* red  = (float*)(lds + RED_OFF);        // 16*10 f32

    const int b = blockIdx.x;
    const int t = threadIdx.x;
    const int lane = t & 63;
    const int wv = t >> 6;       // 0..15
    const int l15 = lane & 15;
    const int g   = lane >> 4;

    // ---- load image + zero rot ----
    const float* xb = x + b*784;
    if (t < 784) {
        int y = t/28, xx = t - y*28;
        imgf[y*32 + xx] = xb[t];
    }
    if (t < 960) rotf[t] = 0.0f;
    __syncthreads();

    // ---- rotate (bilinear, zero pad): one position per thread ----
    if (t < 784) {
        const float2 cn = csn[b];
        const float cs = cn.x, sn = cn.y;
        int y = t/28, xx = t - y*28;
        float dxp = (float)xx - 13.5f;
        float dyp = (float)y  - 13.5f;
        float sx =  cs * dxp + sn * dyp + 13.5f;
        float sy = -sn * dxp + cs * dyp + 13.5f;
        float x0 = floorf(sx), y0 = floorf(sy);
        float wx1 = sx - x0, wx0 = 1.0f - wx1;
        float wy1 = sy - y0, wy0 = 1.0f - wy1;
        int ix0 = (int)x0, iy0 = (int)y0;
        int ix1 = ix0 + 1, iy1 = iy0 + 1;
        int cx0 = min(max(ix0, 0), 27), cy0 = min(max(iy0, 0), 27);
        int cx1 = min(max(ix1, 0), 27), cy1 = min(max(iy1, 0), 27);
        bool vx0 = (ix0 >= 0) & (ix0 <= 27);
        bool vx1 = (ix1 >= 0) & (ix1 <= 27);
        bool vy0 = (iy0 >= 0) & (iy0 <= 27);
        bool vy1 = (iy1 >= 0) & (iy1 <= 27);
        float a00 = imgf[cy0*32 + cx0];
        float a01 = imgf[cy0*32 + cx1];
        float a10 = imgf[cy1*32 + cx0];
        float a11 = imgf[cy1*32 + cx1];
        float v00 = (vx0 & vy0) ? a00 : 0.f;
        float v01 = (vx1 & vy0) ? a01 : 0.f;
        float v10 = (vx0 & vy1) ? a10 : 0.f;
        float v11 = (vx1 & vy1) ? a11 : 0.f;
        float r = v00*wy0*wx0 + v01*wy0*wx1 + v10*wy1*wx0 + v11*wy1*wx1;
        rotf[(y + 1)*32 + (xx + 1)] = r;
    }
    __syncthreads();   // imgf reads done; H1 region free

    // ---- zero H1 pads (row 28 and col 28): 57 cells * 4 chunks ----
    if (t < 228) {
        short8 z8 = {0,0,0,0,0,0,0,0};
        int cell = t >> 2;
        int chunk = t & 3;
        int y, xx;
        if (cell < 29) { y = 28; xx = cell; } else { y = cell - 29; xx = 28; }
        *(short8*)(lds + h1_byte(y, xx, chunk)) = z8;
    }

    // ---- conv1: one position per lane (49/wave), wave-uniform weights ----
    if (lane < 49) {
        int p = wv*49 + lane;
        int py = p/28, px = p - py*28;
        const float* rp = rotf + py*32 + px;   // padded top-left
        float r0 = rp[0],  r1 = rp[1],  r2 = rp[2];
        float r3 = rp[32], r4 = rp[33], r5 = rp[34];
        float r6 = rp[64], r7 = rp[65], r8 = rp[66];
        #pragma unroll
        for (int c8 = 0; c8 < 4; ++c8) {
            half8 vh;
            #pragma unroll
            for (int cc = 0; cc < 8; ++cc) {
                int c = c8*8 + cc;
                const float* wc = w1 + c*9;
                float s = b1[c];
                s = fmaf(wc[0], r0, s); s = fmaf(wc[1], r1, s); s = fmaf(wc[2], r2, s);
                s = fmaf(wc[3], r3, s); s = fmaf(wc[4], r4, s); s = fmaf(wc[5], r5, s);
                s = fmaf(wc[6], r6, s); s = fmaf(wc[7], r7, s); s = fmaf(wc[8], r8, s);
                vh[cc] = (_Float16)fmaxf(s, 0.0f);
            }
            *(half8*)(lds + h1_byte(py, px, c8)) = vh;
        }
    }
    __syncthreads();

    // ---- conv2 via MFMA f16: 52 units (13 sp-tiles x 4 oc-octs) / 16 waves ----
    f32x4 acc[4];
    #pragma unroll
    for (int q = 0; q < 4; ++q) acc[q] = (f32x4){0.f, 0.f, 0.f, 0.f};
    const int u0 = (wv < 4) ? (4*wv) : (16 + 3*(wv - 4));
    const int nq = (wv < 4) ? 4 : 3;

    for (int kk = 0; kk < 9; ++kk) {
        int ky = kk/3;
        int kx = kk - ky*3;
        half8 ah;
        int lastTile = -1;
        #pragma unroll
        for (int q = 0; q < 4; ++q) {
            if (q < nq) {
                int u = u0 + q;
                int tile = u >> 2, oct = u & 3;
                if (tile != lastTile) {
                    int sp = tile*16 + l15;
                    sp = sp > 195 ? 195 : sp;   // clamp garbage rows (discarded later)
                    int oy = sp/14, ox = sp - oy*14;
                    int y = 2*oy + ky, xx = 2*ox + kx;
                    ah = *(const half8*)(lds + h1_byte(y, xx, g));
                    lastTile = tile;
                }
                half8 bh = *(const half8*)(w2frag + (kk*4 + oct)*512 + lane*8);
                acc[q] = __builtin_amdgcn_mfma_f32_16x16x32_f16(ah, bh, acc[q], 0, 0, 0);
            }
        }
    }
    __syncthreads();   // all H1 reads done; reps16 may overwrite

    // ---- epilogue: bias + ReLU -> reps16[oc*196 + sp] (one b64 per unit) ----
    #pragma unroll
    for (int q = 0; q < 4; ++q) {
        if (q < nq) {
            int u = u0 + q;
            int tile = u >> 2, oct = u & 3;
            int oc = oct*16 + l15;
            float bias = b2[oc];
            int sp0 = tile*16 + 4*g;
            if (sp0 + 3 < 196) {
                half4 v;
                #pragma unroll
                for (int j = 0; j < 4; ++j)
                    v[j] = (_Float16)fmaxf(acc[q][j] + bias, 0.0f);
                *(half4*)(reps16 + oc*196 + sp0) = v;
            }
        }
    }
    __syncthreads();

    // ---- pred gemm: out[k] = sum_i reps[i] * pw[i][k], all f16 pairs ----
    float a10[10];
    #pragma unroll
    for (int k = 0; k < 10; ++k) a10[k] = 0.0f;
    const unsigned* pw32 = (const unsigned*)pwt2;     // [k][6272] f16-pairs
    const unsigned* rp32 = (const unsigned*)reps16;   // [6272] f16-pairs
    for (int ip = t; ip < 6272; ip += 1024) {
        unsigned rv = rp32[ip];
#if defined(__has_builtin) && __has_builtin(__builtin_amdgcn_fdot2)
        half2v rh = __builtin_bit_cast(half2v, rv);
        #pragma unroll
        for (int k = 0; k < 10; ++k) {
            half2v ph = __builtin_bit_cast(half2v, pw32[k*6272 + ip]);
            a10[k] = __builtin_amdgcn_fdot2(rh, ph, a10[k], false);
        }
#else
        half2v rh = __builtin_bit_cast(half2v, rv);
        float r0 = (float)rh[0], r1 = (float)rh[1];
        #pragma unroll
        for (int k = 0; k < 10; ++k) {
            half2v ph = __builtin_bit_cast(half2v, pw32[k*6272 + ip]);
            a10[k] = fmaf(r0, (float)ph[0], fmaf(r1, (float)ph[1], a10[k]));
        }
#endif
    }
    #pragma unroll
    for (int k = 0; k < 10; ++k) {
        float v = a10[k];
        #pragma unroll
        for (int off = 32; off; off >>= 1) v += __shfl_down(v, off);
        a10[k] = v;
    }
    if (lane == 0) {
        #pragma unroll
        for (int k = 0; k < 10; ++k) red[wv*10 + k] = a10[k];
    }
    __syncthreads();
    if (t < 10) {
        float s = pb[t];
        #pragma unroll
        for (int w = 0; w < 16; ++w) s += red[w*10 + t];
        out[b*10 + t] = s;
    }
}

// ---------------------------------------------------------------------------
extern "C" void kernel_launch(void* const* d_in, const int* in_sizes, int n_in,
                              void* d_out, int out_size, void* d_ws, size_t ws_size,
                              hipStream_t stream)
{
    const float* x   = (const float*)d_in[0];
    const float* w1  = (const float*)d_in[1];
    const float* b1  = (const float*)d_in[2];
    const float* w2  = (const float*)d_in[3];
    const float* b2  = (const float*)d_in[4];
    const float* pw  = (const float*)d_in[5];
    const float* pb  = (const float*)d_in[6];
    float* out = (float*)d_out;

    const int B = in_sizes[0] / 784;

    // workspace layout (bytes): csn [B*8] | w2frag [36864] | pwt2 [250880]
    char* wsb = (char*)d_ws;
    float2* csn = (float2*)wsb;
    unsigned short* w2frag = (unsigned short*)(wsb + (size_t)B*8);
    unsigned short* pwt2   = (unsigned short*)(wsb + (size_t)B*8 + 36864);

    prep_kernel<<<562, 256, 0, stream>>>(w2, pw, w2frag, pwt2);
    angle_kernel<<<B, 256, 0, stream>>>(x, csn);
    fused_kernel<<<B, 1024, 0, stream>>>(x, w1, b1, b2, w2frag, pwt2, pb, csn, out);
}